// Round 1
// baseline (112.062 us; speedup 1.0000x reference)
//
#include <hip/hip_runtime.h>
#include <cstddef>

// Problem constants (match reference)
#define T_STEPS 32
#define B_SZ    512
#define S_SZ    64
#define F_INPUT 128
#define H1      256
#define H2      256
#define H3      128

typedef _Float16 half_t;
typedef __attribute__((ext_vector_type(8))) _Float16 half8;
typedef __attribute__((ext_vector_type(4))) float   float4v;

// ---------------------------------------------------------------------------
// Kernel 0: pre-split + SWIZZLE weights into MFMA-fragment order (unchanged
// from R6..R9 — verified exact).
//   hi = f16(w) (flushed if f16-denormal), lo = f16((w - hi) * 2^12)
// Tile (n_tile, k_chunk) = 1024 halfs: [0,512) hi, [512,1024) lo, element
// (lr=n&15, quad=kin>>3, j=kin&7) at (quad*16+lr)*8 + j.
// Wave B-frag load = base + lane*8 -> 1 KB fully coalesced, L2-resident.
// ---------------------------------------------------------------------------
__device__ inline void split_store_sw(float w, half_t* out, int n, int k, int kchunks) {
    half_t hi = (half_t)w;
    float hif = (float)hi;
    if (fabsf(hif) < 6.103515625e-05f) { hi = (half_t)0.0f; hif = 0.0f; }
    half_t lo = (half_t)((w - hif) * 4096.0f);
    int n_tile = n >> 4, lr = n & 15;
    int k_chunk = k >> 5, kin = k & 31, quad = kin >> 3, j = kin & 7;
    size_t base = (size_t)(n_tile * kchunks + k_chunk) * 1024;
    size_t off  = base + (size_t)((quad << 4) + lr) * 8 + j;
    out[off]       = hi;
    out[off + 512] = lo;
}

__global__ __launch_bounds__(256)
void prep_w_kernel(const float* __restrict__ W1, const float* __restrict__ W2,
                   const float* __restrict__ W3,
                   half_t* __restrict__ ws1, half_t* __restrict__ ws2,
                   half_t* __restrict__ ws3) {
    int e = blockIdx.x * blockDim.x + threadIdx.x;   // 0..131071
    if (e < H1 * F_INPUT) {                          // 256 x 128, kchunks=4
        split_store_sw(W1[e], ws1, e / F_INPUT, e % F_INPUT, F_INPUT / 32);
    } else if (e < H1 * F_INPUT + H2 * H1) {         // 256 x 256, kchunks=8
        int i = e - H1 * F_INPUT;
        split_store_sw(W2[i], ws2, i / H1, i % H1, H1 / 32);
    } else {                                         // 128 x 256, kchunks=8
        int i = e - H1 * F_INPUT - H2 * H1;
        split_store_sw(W3[i], ws3, i / H2, i % H2, H2 / 32);
    }
}

// ---------------------------------------------------------------------------
// LDS geometry (unchanged): spk aliases As; 49 KB -> 2 blocks/CU.
// ---------------------------------------------------------------------------
#define CUR_STRIDE 260   // floats; cur tile [32][CUR_STRIDE] (also hist scratch)
#define AS_STRIDE  136   // halfs;  rates  [32][AS_STRIDE] (also minmax scratch)
#define SPK_STRIDE 264   // halfs;  spikes [32][SPK_STRIDE]
#define SMEM_CUR   0                      // 32*260*4 = 33280 B
#define SMEM_AS    33280                  // As: 8704 B  } aliased: max = 16896
#define SMEM_SPK   33280                  // spk: 16896 B}
#define SMEM_TOTAL 50176                  // 49 KB; x2 blocks/CU = 98 KB < 160

// Chunk-0 W-fragment preload: issued EARLY (hidden under the previous phase);
// register-destination loads cross s_barrier without a vmcnt drain, so the
// L2/HBM latency of each GEMM's first fragment is overlapped for free.
template<int KCHUNKS, int NT>
__device__ __forceinline__ void preload_w(const half_t* __restrict__ Wsw,
                                          int wave, int lane,
                                          half8* __restrict__ ph,
                                          half8* __restrict__ pl) {
#pragma unroll
    for (int nt = 0; nt < NT; ++nt) {
        const half_t* p = Wsw + ((size_t)(wave * NT + nt) * KCHUNKS) * 1024 + lane * 8;
        ph[nt] = *(const half8*)(p);
        pl[nt] = *(const half8*)(p + 512);
    }
}

// GEMM phase: C = sum A*(hi + 2^-12 lo) + bias, depth-1 W prefetch,
// per-accumulator MFMA order fixed -> bit-identical across rounds.
// PRE=true consumes preloaded chunk-0 fragments (same data, same order).
template<int KCHUNKS, int NT, int ASTRIDE, bool PRE>
__device__ __forceinline__ void gemm_phase(const half_t* __restrict__ Wsw,
                                           const float*  __restrict__ bias,
                                           const half_t* __restrict__ Als,
                                           float* __restrict__ curT,
                                           int wave, int lane,
                                           const half8* __restrict__ pre_h,
                                           const half8* __restrict__ pre_l) {
    const int quad = lane >> 4, lr = lane & 15;
    float4v acc_h[2][NT], acc_l[2][NT];
#pragma unroll
    for (int mt = 0; mt < 2; ++mt)
#pragma unroll
        for (int nt = 0; nt < NT; ++nt) {
            acc_h[mt][nt] = (float4v){0.0f, 0.0f, 0.0f, 0.0f};
            acc_l[mt][nt] = (float4v){0.0f, 0.0f, 0.0f, 0.0f};
        }

    half8 wh[NT], wl[NT];
    if constexpr (PRE) {
#pragma unroll
        for (int nt = 0; nt < NT; ++nt) { wh[nt] = pre_h[nt]; wl[nt] = pre_l[nt]; }
    } else {
#pragma unroll
        for (int nt = 0; nt < NT; ++nt) {
            const half_t* p = Wsw + ((size_t)(wave * NT + nt) * KCHUNKS) * 1024 + lane * 8;
            wh[nt] = *(const half8*)(p);
            wl[nt] = *(const half8*)(p + 512);
        }
    }

#pragma unroll
    for (int c = 0; c < KCHUNKS; ++c) {
        half8 a0 = *(const half8*)(Als + lr * ASTRIDE        + c * 32 + quad * 8);
        half8 a1 = *(const half8*)(Als + (16 + lr) * ASTRIDE + c * 32 + quad * 8);
        half8 nwh[NT], nwl[NT];
        if (c + 1 < KCHUNKS) {
#pragma unroll
            for (int nt = 0; nt < NT; ++nt) {
                const half_t* p =
                    Wsw + ((size_t)(wave * NT + nt) * KCHUNKS + c + 1) * 1024 + lane * 8;
                nwh[nt] = *(const half8*)(p);
                nwl[nt] = *(const half8*)(p + 512);
            }
        }
#pragma unroll
        for (int nt = 0; nt < NT; ++nt) {
            acc_h[0][nt] = __builtin_amdgcn_mfma_f32_16x16x32_f16(a0, wh[nt], acc_h[0][nt], 0, 0, 0);
            acc_h[1][nt] = __builtin_amdgcn_mfma_f32_16x16x32_f16(a1, wh[nt], acc_h[1][nt], 0, 0, 0);
            acc_l[0][nt] = __builtin_amdgcn_mfma_f32_16x16x32_f16(a0, wl[nt], acc_l[0][nt], 0, 0, 0);
            acc_l[1][nt] = __builtin_amdgcn_mfma_f32_16x16x32_f16(a1, wl[nt], acc_l[1][nt], 0, 0, 0);
        }
#pragma unroll
        for (int nt = 0; nt < NT; ++nt) { wh[nt] = nwh[nt]; wl[nt] = nwl[nt]; }
    }

    // epilogue -> curT (C/D layout: col=lane&15, row=quad*4+reg)
#pragma unroll
    for (int nt = 0; nt < NT; ++nt) {
        int col = wave * NT * 16 + nt * 16 + lr;
        float bj = bias[col];
#pragma unroll
        for (int mt = 0; mt < 2; ++mt) {
            int rbase = mt * 16 + quad * 4;
#pragma unroll
            for (int r = 0; r < 4; ++r) {
                float v = acc_h[mt][nt][r] + 2.44140625e-04f * acc_l[mt][nt][r];
                curT[(rbase + r) * CUR_STRIDE + col] = v + bj;
            }
        }
    }
}

// ---------------------------------------------------------------------------
// Mega kernel: one block = one batch b, 512 threads (8 waves).
// CHANGED vs R10:
//  (a) Encode histogram via LDS atomicAdd (fire-and-forget ds_add_f32) into a
//      single shared hist[32][128] f32. The old per-thread `+= ` loop was a
//      serial chain of 32 LDS read-modify-writes (~130 cyc each, compiler
//      cannot reorder possibly-aliasing ds ops): ~4200 cyc, the largest
//      single item on the block critical path. Atomics have no read-back
//      dependency -> ~200 cyc. Counts are exact integers (<=64) under f32
//      adds in any order -> value-identical.
//  (b) Encode split 4-ways over all 512 threads (s-quarters of 16). Halves
//      the per-thread logf chain and uses the previously-idle waves 4-7.
//      min(min of 4 partials) == min(all) -> exact. Partials live in the As
//      region (dead during encode), freeing curT for the 16 KB hist.
//  (c) Chunk-0 W fragments preloaded under the preceding phase (W1 under
//      encode, W2 under LIF1, W3 under LIF2) -> GEMM-entry load latency
//      hidden. Same data, same MFMA order -> bit-identical.
// ---------------------------------------------------------------------------
__global__ __launch_bounds__(512, 4)
void snn_mega_kernel(const float* __restrict__ x,
                     const half_t* __restrict__ ws1, const float* __restrict__ b1,
                     const half_t* __restrict__ ws2, const float* __restrict__ b2,
                     const half_t* __restrict__ ws3, const float* __restrict__ b3,
                     float* __restrict__ out) {
    __shared__ __align__(16) char smem[SMEM_TOTAL];
    float*  curT = (float*) (smem + SMEM_CUR);   // also hist scratch (16 KB)
    half_t* As   = (half_t*)(smem + SMEM_AS);    // aliases spk (As dead first)
    half_t* spk  = (half_t*)(smem + SMEM_SPK);

    const int tid  = threadIdx.x;
    const int b    = blockIdx.x;
    const int wave = tid >> 6;
    const int lane = tid & 63;

    // W1 chunk-0 preload — issues first, returns during encode
    half8 w1h[2], w1l[2];
    preload_w<F_INPUT / 32, 2>(ws1, wave, lane, w1h, w1l);

    // ================= phase 0: latency encode (ALL 512 threads) ==========
    const int f  = tid & 127;
    const int sq = tid >> 7;                     // s-quarter: 16 samples each
    const float* xp = x + (size_t)b * (S_SZ * F_INPUT) + (size_t)(sq * 16) * F_INPUT + f;
    float* hist  = curT;                         // [32][128] f32 = 16 KB
    float* mpart = (float*)(smem + SMEM_AS);     // min[4][128] | max[4][128]

    float v[16];                                 // gated x, registers
#pragma unroll
    for (int s = 0; s < 16; ++s) {
        float val = xp[(size_t)s * F_INPUT];
        v[s] = (val < 0.75f) ? 0.0f : val;
    }
    float mn = 1e30f, mx = -1e30f;
#pragma unroll
    for (int s = 0; s < 16; ++s) {
        mn = fminf(mn, v[s]);
        mx = fmaxf(mx, v[s]);
    }
    mpart[sq * 128 + f]       = mn;
    mpart[512 + sq * 128 + f] = mx;
    // cooperative hist zero (4096 f32); covered by the same barrier
#pragma unroll
    for (int i = 0; i < 8; ++i) hist[tid + i * 512] = 0.0f;
    __syncthreads();

    // exact: min of 4 quarter-mins == min(all); same for max
    float fmn = fminf(fminf(mpart[f],       mpart[128 + f]),
                      fminf(mpart[256 + f], mpart[384 + f]));
    float fmx = fmaxf(fmaxf(mpart[512 + f], mpart[640 + f]),
                      fmaxf(mpart[768 + f], mpart[896 + f]));
    const float denom = fmx - fmn + 1e-8f;
#pragma unroll
    for (int s = 0; s < 16; ++s) {
        float xn = (v[s] - fmn) / denom;
        float d  = fmaxf(xn, 0.0100001f);        // clip(xn, LAT_THR+EPS)
        float tt = logf(d / (d - 0.01f));        // log latency code
        tt = tt * 31.0f;
        tt = tt / 11.512935464920229f;           // float32(log((thr+eps)/eps))
        float tr = rintf(tt);                    // half-to-even == jnp.round
        tr = fminf(fmaxf(tr, 0.0f), 31.0f);
        atomicAdd(&hist[(int)tr * 128 + f], 1.0f);   // ds_add_f32, no chain
    }
    __syncthreads();

    // rates (exact k/64) into As[t][f]; all 512 threads
#pragma unroll
    for (int i = 0; i < 8; ++i) {
        int idx = tid + i * 512;                 // 0..4095 == t*128+f
        int t = idx >> 7, ff = idx & 127;
        As[t * AS_STRIDE + ff] = (half_t)(hist[idx] * 0.015625f);
    }
    __syncthreads();

    // ================= layer 1: GEMM (K=128, N=256) + LIF =================
    gemm_phase<F_INPUT / 32, 2, AS_STRIDE, true>(ws1, b1, As, curT, wave, lane, w1h, w1l);
    __syncthreads();   // all As reads done; spk may now overwrite As region
    half8 w2h[2], w2l[2];                        // W2 preload under LIF1
    preload_w<H1 / 32, 2>(ws2, wave, lane, w2h, w2l);
    if (tid < 256) {
#pragma clang fp contract(off)
        const int h = tid;
        float mem = 0.0f;
#pragma unroll
        for (int t = 0; t < T_STEPS; ++t) {
            float c = curT[t * CUR_STRIDE + h];
            float reset = (mem - 1.0f > 0.0f) ? 1.0f : 0.0f;
            float p = 0.9f * mem;
            p = p + c;
            mem = p - reset;
            spk[t * SPK_STRIDE + h] = (half_t)((mem - 1.0f > 0.0f) ? 1.0f : 0.0f);
        }
    }
    __syncthreads();

    // ================= layer 2: GEMM (K=256, N=256) + LIF =================
    gemm_phase<H1 / 32, 2, SPK_STRIDE, true>(ws2, b2, spk, curT, wave, lane, w2h, w2l);
    __syncthreads();
    half8 w3h[1], w3l[1];                        // W3 preload under LIF2
    preload_w<H2 / 32, 1>(ws3, wave, lane, w3h, w3l);
    if (tid < 256) {
#pragma clang fp contract(off)
        const int h = tid;
        float mem = 0.0f;
#pragma unroll
        for (int t = 0; t < T_STEPS; ++t) {
            float c = curT[t * CUR_STRIDE + h];
            float reset = (mem - 1.0f > 0.0f) ? 1.0f : 0.0f;
            float p = 0.9f * mem;
            p = p + c;
            mem = p - reset;
            spk[t * SPK_STRIDE + h] = (half_t)((mem - 1.0f > 0.0f) ? 1.0f : 0.0f);
        }
    }
    __syncthreads();

    // ================= layer 3: GEMM (K=256, N=128) + LIF -> out ==========
    gemm_phase<H2 / 32, 1, SPK_STRIDE, true>(ws3, b3, spk, curT, wave, lane, w3h, w3l);
    __syncthreads();
    if (tid < H3) {
#pragma clang fp contract(off)
        const int h = tid;
        float mem = 0.0f;
#pragma unroll
        for (int t = 0; t < T_STEPS; ++t) {
            float c = curT[t * CUR_STRIDE + h];
            float reset = (mem - 1.0f > 0.0f) ? 1.0f : 0.0f;
            float p = 0.9f * mem;
            p = p + c;
            mem = p - reset;
            // reference output layout: [t*B + b][h], f32
            out[((size_t)t * B_SZ + b) * H3 + h] = (mem - 1.0f > 0.0f) ? 1.0f : 0.0f;
        }
    }
}

// ---------------------------------------------------------------------------
extern "C" void kernel_launch(void* const* d_in, const int* in_sizes, int n_in,
                              void* d_out, int out_size, void* d_ws, size_t ws_size,
                              hipStream_t stream) {
    const float* x  = (const float*)d_in[0];
    const float* W1 = (const float*)d_in[1];
    const float* b1 = (const float*)d_in[2];
    const float* W2 = (const float*)d_in[3];
    const float* b2 = (const float*)d_in[4];
    const float* W3 = (const float*)d_in[5];
    const float* b3 = (const float*)d_in[6];
    float* out = (float*)d_out;

    char* ws = (char*)d_ws;
    half_t* ws1 = (half_t*)ws;                          // 128 KB (swizzled hi/lo)
    half_t* ws2 = (half_t*)(ws + 128 * 1024);           // 256 KB
    half_t* ws3 = (half_t*)(ws + 384 * 1024);           // 128 KB

    // 0. split + swizzle weights (one dispatch, all layers)
    prep_w_kernel<<<(H1 * F_INPUT + H2 * H1 + H3 * H2) / 256, 256, 0, stream>>>(
        W1, W2, W3, ws1, ws2, ws3);

    // 1. whole network: one block per batch, 8 waves, spikes stay in LDS
    snn_mega_kernel<<<B_SZ, 512, 0, stream>>>(x, ws1, b1, ws2, b2, ws3, b3, out);
}

// Round 2
// 111.569 us; speedup vs baseline: 1.0044x; 1.0044x over previous
//
#include <hip/hip_runtime.h>
#include <cstddef>

// Problem constants (match reference)
#define T_STEPS 32
#define B_SZ    512
#define S_SZ    64
#define F_INPUT 128
#define H1      256
#define H2      256
#define H3      128

typedef _Float16 half_t;
typedef __attribute__((ext_vector_type(8))) _Float16 half8;
typedef __attribute__((ext_vector_type(4))) float   float4v;

// ---------------------------------------------------------------------------
// Kernel 0: pre-split + SWIZZLE weights into MFMA-fragment order (unchanged
// from R6..R9 — verified exact).
//   hi = f16(w) (flushed if f16-denormal), lo = f16((w - hi) * 2^12)
// Tile (n_tile, k_chunk) = 1024 halfs: [0,512) hi, [512,1024) lo, element
// (lr=n&15, quad=kin>>3, j=kin&7) at (quad*16+lr)*8 + j.
// Wave B-frag load = base + lane*8 -> 1 KB fully coalesced, L2-resident.
// ---------------------------------------------------------------------------
__device__ inline void split_store_sw(float w, half_t* out, int n, int k, int kchunks) {
    half_t hi = (half_t)w;
    float hif = (float)hi;
    if (fabsf(hif) < 6.103515625e-05f) { hi = (half_t)0.0f; hif = 0.0f; }
    half_t lo = (half_t)((w - hif) * 4096.0f);
    int n_tile = n >> 4, lr = n & 15;
    int k_chunk = k >> 5, kin = k & 31, quad = kin >> 3, j = kin & 7;
    size_t base = (size_t)(n_tile * kchunks + k_chunk) * 1024;
    size_t off  = base + (size_t)((quad << 4) + lr) * 8 + j;
    out[off]       = hi;
    out[off + 512] = lo;
}

__global__ __launch_bounds__(256)
void prep_w_kernel(const float* __restrict__ W1, const float* __restrict__ W2,
                   const float* __restrict__ W3,
                   half_t* __restrict__ ws1, half_t* __restrict__ ws2,
                   half_t* __restrict__ ws3) {
    int e = blockIdx.x * blockDim.x + threadIdx.x;   // 0..131071
    if (e < H1 * F_INPUT) {                          // 256 x 128, kchunks=4
        split_store_sw(W1[e], ws1, e / F_INPUT, e % F_INPUT, F_INPUT / 32);
    } else if (e < H1 * F_INPUT + H2 * H1) {         // 256 x 256, kchunks=8
        int i = e - H1 * F_INPUT;
        split_store_sw(W2[i], ws2, i / H1, i % H1, H1 / 32);
    } else {                                         // 128 x 256, kchunks=8
        int i = e - H1 * F_INPUT - H3 * H2 - H2 * H1 + H3 * H2;
        i = e - H1 * F_INPUT - H2 * H1;
        split_store_sw(W3[i], ws3, i / H2, i % H2, H2 / 32);
    }
}

// ---------------------------------------------------------------------------
// LDS geometry (unchanged from R7/R9): spk aliases As; 49 KB -> 2 blocks/CU.
// ---------------------------------------------------------------------------
#define CUR_STRIDE 260   // floats; cur tile [32][CUR_STRIDE] (also hist scratch)
#define AS_STRIDE  136   // halfs;  rates  [32][AS_STRIDE]
#define SPK_STRIDE 264   // halfs;  spikes [32][SPK_STRIDE]
#define SMEM_CUR   0                      // 32*260*4 = 33280 B
#define SMEM_AS    33280                  // As: 8704 B  } aliased: max = 16896
#define SMEM_SPK   33280                  // spk: 16896 B}
#define SMEM_TOTAL 50176                  // 49 KB; x2 blocks/CU = 98 KB < 160

// GEMM phase (unchanged from R9): C = sum A*(hi + 2^-12 lo) + bias, depth-1
// W prefetch, per-accumulator MFMA order fixed -> bit-identical across rounds.
template<int KCHUNKS, int NT, int ASTRIDE>
__device__ __forceinline__ void gemm_phase(const half_t* __restrict__ Wsw,
                                           const float*  __restrict__ bias,
                                           const half_t* __restrict__ Als,
                                           float* __restrict__ curT,
                                           int wave, int lane) {
    const int quad = lane >> 4, lr = lane & 15;
    float4v acc_h[2][NT], acc_l[2][NT];
#pragma unroll
    for (int mt = 0; mt < 2; ++mt)
#pragma unroll
        for (int nt = 0; nt < NT; ++nt) {
            acc_h[mt][nt] = (float4v){0.0f, 0.0f, 0.0f, 0.0f};
            acc_l[mt][nt] = (float4v){0.0f, 0.0f, 0.0f, 0.0f};
        }

    half8 wh[NT], wl[NT];
#pragma unroll
    for (int nt = 0; nt < NT; ++nt) {
        const half_t* p = Wsw + ((size_t)(wave * NT + nt) * KCHUNKS) * 1024 + lane * 8;
        wh[nt] = *(const half8*)(p);
        wl[nt] = *(const half8*)(p + 512);
    }

#pragma unroll
    for (int c = 0; c < KCHUNKS; ++c) {
        half8 a0 = *(const half8*)(Als + lr * ASTRIDE        + c * 32 + quad * 8);
        half8 a1 = *(const half8*)(Als + (16 + lr) * ASTRIDE + c * 32 + quad * 8);
        half8 nwh[NT], nwl[NT];
        if (c + 1 < KCHUNKS) {
#pragma unroll
            for (int nt = 0; nt < NT; ++nt) {
                const half_t* p =
                    Wsw + ((size_t)(wave * NT + nt) * KCHUNKS + c + 1) * 1024 + lane * 8;
                nwh[nt] = *(const half8*)(p);
                nwl[nt] = *(const half8*)(p + 512);
            }
        }
#pragma unroll
        for (int nt = 0; nt < NT; ++nt) {
            acc_h[0][nt] = __builtin_amdgcn_mfma_f32_16x16x32_f16(a0, wh[nt], acc_h[0][nt], 0, 0, 0);
            acc_h[1][nt] = __builtin_amdgcn_mfma_f32_16x16x32_f16(a1, wh[nt], acc_h[1][nt], 0, 0, 0);
            acc_l[0][nt] = __builtin_amdgcn_mfma_f32_16x16x32_f16(a0, wl[nt], acc_l[0][nt], 0, 0, 0);
            acc_l[1][nt] = __builtin_amdgcn_mfma_f32_16x16x32_f16(a1, wl[nt], acc_l[1][nt], 0, 0, 0);
        }
#pragma unroll
        for (int nt = 0; nt < NT; ++nt) { wh[nt] = nwh[nt]; wl[nt] = nwl[nt]; }
    }

    // epilogue -> curT (C/D layout: col=lane&15, row=quad*4+reg)
#pragma unroll
    for (int nt = 0; nt < NT; ++nt) {
        int col = wave * NT * 16 + nt * 16 + lr;
        float bj = bias[col];
#pragma unroll
        for (int mt = 0; mt < 2; ++mt) {
            int rbase = mt * 16 + quad * 4;
#pragma unroll
            for (int r = 0; r < 4; ++r) {
                float v = acc_h[mt][nt][r] + 2.44140625e-04f * acc_l[mt][nt][r];
                curT[(rbase + r) * CUR_STRIDE + col] = v + bj;
            }
        }
    }
}

// ---------------------------------------------------------------------------
// Mega kernel: one block = one batch b, 512 threads (8 waves).
// CHANGED vs R0 (single-variable experiment; R1's 3-way change regressed
// 98.9 -> 112 us and is fully reverted):
//   ONLY delta: the encode histogram scatter `hist[...] += 1.0f` (a serial
//   chain of 32 possibly-aliasing LDS read-modify-writes, ~130 cyc each ->
//   ~4.2k cyc on the block critical path) is replaced by atomicAdd
//   (fire-and-forget ds_add_f32, no read-back dependency). Ownership is
//   unchanged: each thread still exclusively owns its (sh, *, f) column, so
//   ordering is irrelevant and counts (integers <= 32 in f32) are
//   bit-identical. Everything else is byte-identical to the 98.9 us R0.
// ---------------------------------------------------------------------------
__global__ __launch_bounds__(512, 4)
void snn_mega_kernel(const float* __restrict__ x,
                     const half_t* __restrict__ ws1, const float* __restrict__ b1,
                     const half_t* __restrict__ ws2, const float* __restrict__ b2,
                     const half_t* __restrict__ ws3, const float* __restrict__ b3,
                     float* __restrict__ out) {
    __shared__ __align__(16) char smem[SMEM_TOTAL];
    float*  curT = (float*) (smem + SMEM_CUR);   // also hist/minmax scratch
    half_t* As   = (half_t*)(smem + SMEM_AS);    // aliases spk (As dead first)
    half_t* spk  = (half_t*)(smem + SMEM_SPK);

    const int tid  = threadIdx.x;
    const int b    = blockIdx.x;
    const int wave = tid >> 6;
    const int lane = tid & 63;

    // ================= phase 0: latency encode (threads 0..255) ===========
    const int f  = tid & 127;
    const int sh = (tid >> 7) & 1;               // s-half: 0 -> s 0..31, 1 -> 32..63
    const float* xp = x + (size_t)b * (S_SZ * F_INPUT) + (size_t)sh * 32 * F_INPUT + f;
    float* scratch = curT;

    float v[32];                                 // gated x, registers (no spill:
                                                 // kernel peak pressure is the
                                                 // ~110-VGPR GEMM phase, cap 128)
    if (tid < 256) {
        // burst all 32 loads (independent, all in flight), gate at ENC_THR
#pragma unroll
        for (int s = 0; s < 32; ++s) {
            float val = xp[(size_t)s * F_INPUT];
            v[s] = (val < 0.75f) ? 0.0f : val;
        }
        float mn = 1e30f, mx = -1e30f;
#pragma unroll
        for (int s = 0; s < 32; ++s) {
            mn = fminf(mn, v[s]);
            mx = fmaxf(mx, v[s]);
        }
        scratch[sh * 128 + f]       = mn;
        scratch[256 + sh * 128 + f] = mx;
    }
    __syncthreads();
    // exact: min(min half0, min half1) == min(all); same for max
    float fmn = fminf(scratch[f], scratch[128 + f]);
    float fmx = fmaxf(scratch[256 + f], scratch[384 + f]);
    __syncthreads();

    if (tid < 256) {
        float* hist = scratch;                   // hist[2][32][128] f32
#pragma unroll
        for (int t = 0; t < T_STEPS; ++t) hist[sh * 4096 + t * 128 + f] = 0.0f;
        // no barrier needed: each thread touches only its own (sh,*,f) cells
        const float denom = fmx - fmn + 1e-8f;
#pragma unroll
        for (int s = 0; s < 32; ++s) {
            float g = v[s];                      // reuse register value
            float xn = (g - fmn) / denom;
            float d  = fmaxf(xn, 0.0100001f);        // clip(xn, LAT_THR+EPS)
            float tt = logf(d / (d - 0.01f));        // log latency code
            tt = tt * 31.0f;
            tt = tt / 11.512935464920229f;           // float32(log((thr+eps)/eps))
            float tr = rintf(tt);                    // half-to-even == jnp.round
            tr = fminf(fmaxf(tr, 0.0f), 31.0f);
            // ds_add_f32 (no return): kills the 32-deep serial RMW chain.
            // Each (sh,*,f) column still owned by exactly ONE thread ->
            // order-independent integer counts, bit-identical result.
            atomicAdd(&hist[sh * 4096 + (int)tr * 128 + f], 1.0f);
        }
    }
    __syncthreads();

    // merge halves -> rates (exact k/64) into As[t][f]; all 512 threads
#pragma unroll
    for (int i = 0; i < 8; ++i) {
        int idx = tid + i * 512;                 // 0..4095
        int t = idx >> 7, ff = idx & 127;
        float cnt = scratch[t * 128 + ff] + scratch[4096 + t * 128 + ff];
        As[t * AS_STRIDE + ff] = (half_t)(cnt * 0.015625f);
    }
    __syncthreads();

    // ================= layer 1: GEMM (K=128, N=256) + LIF =================
    gemm_phase<F_INPUT / 32, 2, AS_STRIDE>(ws1, b1, As, curT, wave, lane);
    __syncthreads();   // all As reads done; spk may now overwrite As region
    if (tid < 256) {
#pragma clang fp contract(off)
        const int h = tid;
        float mem = 0.0f;
#pragma unroll
        for (int t = 0; t < T_STEPS; ++t) {
            float c = curT[t * CUR_STRIDE + h];
            float reset = (mem - 1.0f > 0.0f) ? 1.0f : 0.0f;
            float p = 0.9f * mem;
            p = p + c;
            mem = p - reset;
            spk[t * SPK_STRIDE + h] = (half_t)((mem - 1.0f > 0.0f) ? 1.0f : 0.0f);
        }
    }
    __syncthreads();

    // ================= layer 2: GEMM (K=256, N=256) + LIF =================
    gemm_phase<H1 / 32, 2, SPK_STRIDE>(ws2, b2, spk, curT, wave, lane);
    __syncthreads();
    if (tid < 256) {
#pragma clang fp contract(off)
        const int h = tid;
        float mem = 0.0f;
#pragma unroll
        for (int t = 0; t < T_STEPS; ++t) {
            float c = curT[t * CUR_STRIDE + h];
            float reset = (mem - 1.0f > 0.0f) ? 1.0f : 0.0f;
            float p = 0.9f * mem;
            p = p + c;
            mem = p - reset;
            spk[t * SPK_STRIDE + h] = (half_t)((mem - 1.0f > 0.0f) ? 1.0f : 0.0f);
        }
    }
    __syncthreads();

    // ================= layer 3: GEMM (K=256, N=128) + LIF -> out ==========
    gemm_phase<H2 / 32, 1, SPK_STRIDE>(ws3, b3, spk, curT, wave, lane);
    __syncthreads();
    if (tid < H3) {
#pragma clang fp contract(off)
        const int h = tid;
        float mem = 0.0f;
#pragma unroll
        for (int t = 0; t < T_STEPS; ++t) {
            float c = curT[t * CUR_STRIDE + h];
            float reset = (mem - 1.0f > 0.0f) ? 1.0f : 0.0f;
            float p = 0.9f * mem;
            p = p + c;
            mem = p - reset;
            // reference output layout: [t*B + b][h], f32
            out[((size_t)t * B_SZ + b) * H3 + h] = (mem - 1.0f > 0.0f) ? 1.0f : 0.0f;
        }
    }
}

// ---------------------------------------------------------------------------
extern "C" void kernel_launch(void* const* d_in, const int* in_sizes, int n_in,
                              void* d_out, int out_size, void* d_ws, size_t ws_size,
                              hipStream_t stream) {
    const float* x  = (const float*)d_in[0];
    const float* W1 = (const float*)d_in[1];
    const float* b1 = (const float*)d_in[2];
    const float* W2 = (const float*)d_in[3];
    const float* b2 = (const float*)d_in[4];
    const float* W3 = (const float*)d_in[5];
    const float* b3 = (const float*)d_in[6];
    float* out = (float*)d_out;

    char* ws = (char*)d_ws;
    half_t* ws1 = (half_t*)ws;                          // 128 KB (swizzled hi/lo)
    half_t* ws2 = (half_t*)(ws + 128 * 1024);           // 256 KB
    half_t* ws3 = (half_t*)(ws + 384 * 1024);           // 128 KB

    // 0. split + swizzle weights (one dispatch, all layers)
    prep_w_kernel<<<(H1 * F_INPUT + H2 * H1 + H3 * H2) / 256, 256, 0, stream>>>(
        W1, W2, W3, ws1, ws2, ws3);

    // 1. whole network: one block per batch, 8 waves, spikes stay in LDS
    snn_mega_kernel<<<B_SZ, 512, 0, stream>>>(x, ws1, b1, ws2, b2, ws3, b3, out);
}

// Round 3
// 97.135 us; speedup vs baseline: 1.1537x; 1.1486x over previous
//
#include <hip/hip_runtime.h>
#include <cstddef>

// Problem constants (match reference)
#define T_STEPS 32
#define B_SZ    512
#define S_SZ    64
#define F_INPUT 128
#define H1      256
#define H2      256
#define H3      128

typedef _Float16 half_t;
typedef __attribute__((ext_vector_type(8))) _Float16 half8;
typedef __attribute__((ext_vector_type(4))) float   float4v;

// ---------------------------------------------------------------------------
// Kernel 0: pre-split + SWIZZLE weights into MFMA-fragment order (unchanged
// from R6..R9 — verified exact).
//   hi = f16(w) (flushed if f16-denormal), lo = f16((w - hi) * 2^12)
// Tile (n_tile, k_chunk) = 1024 halfs: [0,512) hi, [512,1024) lo, element
// (lr=n&15, quad=kin>>3, j=kin&7) at (quad*16+lr)*8 + j.
// Wave B-frag load = base + lane*8 -> 1 KB fully coalesced, L2-resident.
// ---------------------------------------------------------------------------
__device__ inline void split_store_sw(float w, half_t* out, int n, int k, int kchunks) {
    half_t hi = (half_t)w;
    float hif = (float)hi;
    if (fabsf(hif) < 6.103515625e-05f) { hi = (half_t)0.0f; hif = 0.0f; }
    half_t lo = (half_t)((w - hif) * 4096.0f);
    int n_tile = n >> 4, lr = n & 15;
    int k_chunk = k >> 5, kin = k & 31, quad = kin >> 3, j = kin & 7;
    size_t base = (size_t)(n_tile * kchunks + k_chunk) * 1024;
    size_t off  = base + (size_t)((quad << 4) + lr) * 8 + j;
    out[off]       = hi;
    out[off + 512] = lo;
}

__global__ __launch_bounds__(256)
void prep_w_kernel(const float* __restrict__ W1, const float* __restrict__ W2,
                   const float* __restrict__ W3,
                   half_t* __restrict__ ws1, half_t* __restrict__ ws2,
                   half_t* __restrict__ ws3) {
    int e = blockIdx.x * blockDim.x + threadIdx.x;   // 0..131071
    if (e < H1 * F_INPUT) {                          // 256 x 128, kchunks=4
        split_store_sw(W1[e], ws1, e / F_INPUT, e % F_INPUT, F_INPUT / 32);
    } else if (e < H1 * F_INPUT + H2 * H1) {         // 256 x 256, kchunks=8
        int i = e - H1 * F_INPUT;
        split_store_sw(W2[i], ws2, i / H1, i % H1, H1 / 32);
    } else {                                         // 128 x 256, kchunks=8
        int i = e - H1 * F_INPUT - H2 * H1;
        split_store_sw(W3[i], ws3, i / H2, i % H2, H2 / 32);
    }
}

// ---------------------------------------------------------------------------
// LDS geometry (unchanged from R7/R9): spk aliases As; 49 KB -> 2 blocks/CU.
// ---------------------------------------------------------------------------
#define CUR_STRIDE 260   // floats; cur tile [32][CUR_STRIDE] (also hist scratch)
#define AS_STRIDE  136   // halfs;  rates  [32][AS_STRIDE]
#define SPK_STRIDE 264   // halfs;  spikes [32][SPK_STRIDE]
#define SMEM_CUR   0                      // 32*260*4 = 33280 B
#define SMEM_AS    33280                  // As: 8704 B  } aliased: max = 16896
#define SMEM_SPK   33280                  // spk: 16896 B}
#define SMEM_TOTAL 50176                  // 49 KB; x2 blocks/CU = 98 KB < 160

// GEMM phase (unchanged from R9): C = sum A*(hi + 2^-12 lo) + bias, depth-1
// W prefetch, per-accumulator MFMA order fixed -> bit-identical across rounds.
template<int KCHUNKS, int NT, int ASTRIDE>
__device__ __forceinline__ void gemm_phase(const half_t* __restrict__ Wsw,
                                           const float*  __restrict__ bias,
                                           const half_t* __restrict__ Als,
                                           float* __restrict__ curT,
                                           int wave, int lane) {
    const int quad = lane >> 4, lr = lane & 15;
    float4v acc_h[2][NT], acc_l[2][NT];
#pragma unroll
    for (int mt = 0; mt < 2; ++mt)
#pragma unroll
        for (int nt = 0; nt < NT; ++nt) {
            acc_h[mt][nt] = (float4v){0.0f, 0.0f, 0.0f, 0.0f};
            acc_l[mt][nt] = (float4v){0.0f, 0.0f, 0.0f, 0.0f};
        }

    half8 wh[NT], wl[NT];
#pragma unroll
    for (int nt = 0; nt < NT; ++nt) {
        const half_t* p = Wsw + ((size_t)(wave * NT + nt) * KCHUNKS) * 1024 + lane * 8;
        wh[nt] = *(const half8*)(p);
        wl[nt] = *(const half8*)(p + 512);
    }

#pragma unroll
    for (int c = 0; c < KCHUNKS; ++c) {
        half8 a0 = *(const half8*)(Als + lr * ASTRIDE        + c * 32 + quad * 8);
        half8 a1 = *(const half8*)(Als + (16 + lr) * ASTRIDE + c * 32 + quad * 8);
        half8 nwh[NT], nwl[NT];
        if (c + 1 < KCHUNKS) {
#pragma unroll
            for (int nt = 0; nt < NT; ++nt) {
                const half_t* p =
                    Wsw + ((size_t)(wave * NT + nt) * KCHUNKS + c + 1) * 1024 + lane * 8;
                nwh[nt] = *(const half8*)(p);
                nwl[nt] = *(const half8*)(p + 512);
            }
        }
#pragma unroll
        for (int nt = 0; nt < NT; ++nt) {
            acc_h[0][nt] = __builtin_amdgcn_mfma_f32_16x16x32_f16(a0, wh[nt], acc_h[0][nt], 0, 0, 0);
            acc_h[1][nt] = __builtin_amdgcn_mfma_f32_16x16x32_f16(a1, wh[nt], acc_h[1][nt], 0, 0, 0);
            acc_l[0][nt] = __builtin_amdgcn_mfma_f32_16x16x32_f16(a0, wl[nt], acc_l[0][nt], 0, 0, 0);
            acc_l[1][nt] = __builtin_amdgcn_mfma_f32_16x16x32_f16(a1, wl[nt], acc_l[1][nt], 0, 0, 0);
        }
#pragma unroll
        for (int nt = 0; nt < NT; ++nt) { wh[nt] = nwh[nt]; wl[nt] = nwl[nt]; }
    }

    // epilogue -> curT (C/D layout: col=lane&15, row=quad*4+reg)
#pragma unroll
    for (int nt = 0; nt < NT; ++nt) {
        int col = wave * NT * 16 + nt * 16 + lr;
        float bj = bias[col];
#pragma unroll
        for (int mt = 0; mt < 2; ++mt) {
            int rbase = mt * 16 + quad * 4;
#pragma unroll
            for (int r = 0; r < 4; ++r) {
                float v = acc_h[mt][nt][r] + 2.44140625e-04f * acc_l[mt][nt][r];
                curT[(rbase + r) * CUR_STRIDE + col] = v + bj;
            }
        }
    }
}

// ---------------------------------------------------------------------------
// Mega kernel: one block = one batch b, 512 threads (8 waves).
// CHANGED vs R2 (single-variable, second attempt at the same mechanism):
//   R2 used atomicAdd(float*) on LDS, which without -munsafe-fp-atomics
//   lowers to a CAS RETRY LOOP -> divergent control flow mid-kernel ->
//   regalloc demoted v[32] etc. to scratch (VGPR_Count fell to 48) ->
//   scratch traffic against a poisoned L2 = +12 us. Evidence: R2 counters
//   (VGPR=48, mega 44.6 us, latency-bound profile).
//   THIS round: hist in u32 + atomicAdd(unsigned*) -> single native
//   ds_add_u32 (fire-and-forget, no loop, no return dependency). Same
//   ownership (each (sh,f) column touched by exactly one thread), counts are
//   exact integers <= 32 per half; u32->f32 conversion and *2^-6 exact ->
//   bit-identical output. Everything else byte-identical to the 98.9 us R0.
// ---------------------------------------------------------------------------
__global__ __launch_bounds__(512, 4)
void snn_mega_kernel(const float* __restrict__ x,
                     const half_t* __restrict__ ws1, const float* __restrict__ b1,
                     const half_t* __restrict__ ws2, const float* __restrict__ b2,
                     const half_t* __restrict__ ws3, const float* __restrict__ b3,
                     float* __restrict__ out) {
    __shared__ __align__(16) char smem[SMEM_TOTAL];
    float*  curT = (float*) (smem + SMEM_CUR);   // also hist/minmax scratch
    half_t* As   = (half_t*)(smem + SMEM_AS);    // aliases spk (As dead first)
    half_t* spk  = (half_t*)(smem + SMEM_SPK);

    const int tid  = threadIdx.x;
    const int b    = blockIdx.x;
    const int wave = tid >> 6;
    const int lane = tid & 63;

    // ================= phase 0: latency encode (threads 0..255) ===========
    const int f  = tid & 127;
    const int sh = (tid >> 7) & 1;               // s-half: 0 -> s 0..31, 1 -> 32..63
    const float* xp = x + (size_t)b * (S_SZ * F_INPUT) + (size_t)sh * 32 * F_INPUT + f;
    float* scratch = curT;

    float v[32];                                 // gated x, registers (no spill:
                                                 // kernel peak pressure is the
                                                 // ~110-VGPR GEMM phase, cap 128)
    if (tid < 256) {
        // burst all 32 loads (independent, all in flight), gate at ENC_THR
#pragma unroll
        for (int s = 0; s < 32; ++s) {
            float val = xp[(size_t)s * F_INPUT];
            v[s] = (val < 0.75f) ? 0.0f : val;
        }
        float mn = 1e30f, mx = -1e30f;
#pragma unroll
        for (int s = 0; s < 32; ++s) {
            mn = fminf(mn, v[s]);
            mx = fmaxf(mx, v[s]);
        }
        scratch[sh * 128 + f]       = mn;
        scratch[256 + sh * 128 + f] = mx;
    }
    __syncthreads();
    // exact: min(min half0, min half1) == min(all); same for max
    float fmn = fminf(scratch[f], scratch[128 + f]);
    float fmx = fmaxf(scratch[256 + f], scratch[384 + f]);
    __syncthreads();

    unsigned* histu = (unsigned*)scratch;        // hist[2][32][128] u32
    if (tid < 256) {
#pragma unroll
        for (int t = 0; t < T_STEPS; ++t) histu[sh * 4096 + t * 128 + f] = 0u;
        // no barrier needed: each thread touches only its own (sh,*,f) cells
        const float denom = fmx - fmn + 1e-8f;
#pragma unroll
        for (int s = 0; s < 32; ++s) {
            float g = v[s];                      // reuse register value
            float xn = (g - fmn) / denom;
            float d  = fmaxf(xn, 0.0100001f);        // clip(xn, LAT_THR+EPS)
            float tt = logf(d / (d - 0.01f));        // log latency code
            tt = tt * 31.0f;
            tt = tt / 11.512935464920229f;           // float32(log((thr+eps)/eps))
            float tr = rintf(tt);                    // half-to-even == jnp.round
            tr = fminf(fmaxf(tr, 0.0f), 31.0f);
            // native ds_add_u32 (no return, no CAS loop): kills the 32-deep
            // serial RMW chain without perturbing control flow / regalloc.
            atomicAdd(&histu[sh * 4096 + (int)tr * 128 + f], 1u);
        }
    }
    __syncthreads();

    // merge halves -> rates (exact k/64) into As[t][f]; all 512 threads
#pragma unroll
    for (int i = 0; i < 8; ++i) {
        int idx = tid + i * 512;                 // 0..4095
        int t = idx >> 7, ff = idx & 127;
        float cnt = (float)(histu[t * 128 + ff] + histu[4096 + t * 128 + ff]);
        As[t * AS_STRIDE + ff] = (half_t)(cnt * 0.015625f);
    }
    __syncthreads();

    // ================= layer 1: GEMM (K=128, N=256) + LIF =================
    gemm_phase<F_INPUT / 32, 2, AS_STRIDE>(ws1, b1, As, curT, wave, lane);
    __syncthreads();   // all As reads done; spk may now overwrite As region
    if (tid < 256) {
#pragma clang fp contract(off)
        const int h = tid;
        float mem = 0.0f;
#pragma unroll
        for (int t = 0; t < T_STEPS; ++t) {
            float c = curT[t * CUR_STRIDE + h];
            float reset = (mem - 1.0f > 0.0f) ? 1.0f : 0.0f;
            float p = 0.9f * mem;
            p = p + c;
            mem = p - reset;
            spk[t * SPK_STRIDE + h] = (half_t)((mem - 1.0f > 0.0f) ? 1.0f : 0.0f);
        }
    }
    __syncthreads();

    // ================= layer 2: GEMM (K=256, N=256) + LIF =================
    gemm_phase<H1 / 32, 2, SPK_STRIDE>(ws2, b2, spk, curT, wave, lane);
    __syncthreads();
    if (tid < 256) {
#pragma clang fp contract(off)
        const int h = tid;
        float mem = 0.0f;
#pragma unroll
        for (int t = 0; t < T_STEPS; ++t) {
            float c = curT[t * CUR_STRIDE + h];
            float reset = (mem - 1.0f > 0.0f) ? 1.0f : 0.0f;
            float p = 0.9f * mem;
            p = p + c;
            mem = p - reset;
            spk[t * SPK_STRIDE + h] = (half_t)((mem - 1.0f > 0.0f) ? 1.0f : 0.0f);
        }
    }
    __syncthreads();

    // ================= layer 3: GEMM (K=256, N=128) + LIF -> out ==========
    gemm_phase<H2 / 32, 1, SPK_STRIDE>(ws3, b3, spk, curT, wave, lane);
    __syncthreads();
    if (tid < H3) {
#pragma clang fp contract(off)
        const int h = tid;
        float mem = 0.0f;
#pragma unroll
        for (int t = 0; t < T_STEPS; ++t) {
            float c = curT[t * CUR_STRIDE + h];
            float reset = (mem - 1.0f > 0.0f) ? 1.0f : 0.0f;
            float p = 0.9f * mem;
            p = p + c;
            mem = p - reset;
            // reference output layout: [t*B + b][h], f32
            out[((size_t)t * B_SZ + b) * H3 + h] = (mem - 1.0f > 0.0f) ? 1.0f : 0.0f;
        }
    }
}

// ---------------------------------------------------------------------------
extern "C" void kernel_launch(void* const* d_in, const int* in_sizes, int n_in,
                              void* d_out, int out_size, void* d_ws, size_t ws_size,
                              hipStream_t stream) {
    const float* x  = (const float*)d_in[0];
    const float* W1 = (const float*)d_in[1];
    const float* b1 = (const float*)d_in[2];
    const float* W2 = (const float*)d_in[3];
    const float* b2 = (const float*)d_in[4];
    const float* W3 = (const float*)d_in[5];
    const float* b3 = (const float*)d_in[6];
    float* out = (float*)d_out;

    char* ws = (char*)d_ws;
    half_t* ws1 = (half_t*)ws;                          // 128 KB (swizzled hi/lo)
    half_t* ws2 = (half_t*)(ws + 128 * 1024);           // 256 KB
    half_t* ws3 = (half_t*)(ws + 384 * 1024);           // 128 KB

    // 0. split + swizzle weights (one dispatch, all layers)
    prep_w_kernel<<<(H1 * F_INPUT + H2 * H1 + H3 * H2) / 256, 256, 0, stream>>>(
        W1, W2, W3, ws1, ws2, ws3);

    // 1. whole network: one block per batch, 8 waves, spikes stay in LDS
    snn_mega_kernel<<<B_SZ, 512, 0, stream>>>(x, ws1, b1, ws2, b2, ws3, b3, out);
}